// Round 5
// baseline (626.849 us; speedup 1.0000x reference)
//
#include <hip/hip_runtime.h>
#include <hip/hip_bf16.h>
#include <stdint.h>
#include <math.h>

// Problem constants (fixed by reference)
#define NROWS   32768      // 8*4096
#define CDIM    768
#define NCODES  2048
#define NGROUPS 8          // col-groups (one 256-wide n-tile per group)
#define BM 256
#define BN 256
#define BK 64
#define KSTEPS (CDIM / BK)                  // 12
#define ESCALE 2048.0f                      // 2^11: lifts e into e4m3 range
#define INV2ESCALE (2.0f / ESCALE)          // folds the "-2 * dot" back
#define TILE_STRIDE (2 * BM * BK)           // A+B per ring slot (32 KB)
#define SCALE1 0x7F7F7F7F                   // E8M0 = 127 in every byte -> x1.0

typedef __attribute__((ext_vector_type(16))) float f32x16;
typedef __attribute__((ext_vector_type(8)))  int   i32x8;

#define BARM() asm volatile("s_barrier" ::: "memory")
#define SB0()  __builtin_amdgcn_sched_barrier(0)

// ---------- helpers ----------
__device__ __forceinline__ void async_load16(const void* gsrc, void* ldst) {
    __builtin_amdgcn_global_load_lds(
        (const __attribute__((address_space(1))) unsigned int*)gsrc,
        (__attribute__((address_space(3))) unsigned int*)ldst,
        16 /*bytes*/, 0 /*offset*/, 0 /*aux*/);
}

__device__ __forceinline__ unsigned int pack4_fp8(float x, float y, float z, float w) {
    int v = __builtin_amdgcn_cvt_pk_fp8_f32(x, y, 0, false);   // bytes 0,1
    v     = __builtin_amdgcn_cvt_pk_fp8_f32(z, w, v, true);    // bytes 2,3
    return (unsigned int)v;
}

// granule swizzle: LDS slot sl of row r holds global granule sl ^ ((r>>1)&3)
// (XOR involution: reader wanting global granule g reads slot g ^ ((r>>1)&3)).
__device__ __forceinline__ int swz(int sl, int r) { return sl ^ ((r >> 1) & 3); }

// ---------- 1) fused: z -> fp8  AND  e -> fp8*2048 + ||e||^2 + zero hist ----------
#define ZBLOCKS 6144       // 25165824 elems / (256 thr * 16 elem)
__global__ __launch_bounds__(256) void convert_fused(const float* __restrict__ z,
                                                     const float* __restrict__ e,
                                                     unsigned char* __restrict__ z8,
                                                     unsigned char* __restrict__ e8,
                                                     float* __restrict__ enorm,
                                                     unsigned int* __restrict__ counts) {
    int b = blockIdx.x;
    if (b < ZBLOCKS) {
        // fully-coalesced: each instruction's 64 lanes touch 1 KB contiguous
        const float4* zp = (const float4*)z + (size_t)b * 1024;
        unsigned int* o8 = (unsigned int*)z8 + (size_t)b * 1024;
        #pragma unroll
        for (int k2 = 0; k2 < 4; ++k2) {
            float4 a = zp[k2 * 256 + threadIdx.x];
            o8[k2 * 256 + threadIdx.x] = pack4_fp8(a.x, a.y, a.z, a.w);
        }
    } else {
        int k = b - ZBLOCKS;                      // one code per block
        int t = threadIdx.x;
        float s = 0.f;
        if (t < 192) {                            // 192 * 4 = 768 elems
            float4 v = ((const float4*)(e + (size_t)k * CDIM))[t];
            s = v.x * v.x + v.y * v.y + v.z * v.z + v.w * v.w;
            ((unsigned int*)(e8 + (size_t)k * CDIM))[t] =
                pack4_fp8(v.x * ESCALE, v.y * ESCALE, v.z * ESCALE, v.w * ESCALE);
        }
        #pragma unroll
        for (int o = 32; o > 0; o >>= 1) s += __shfl_down(s, o);
        __shared__ float red[4];
        if ((t & 63) == 0) red[t >> 6] = s;
        __syncthreads();
        if (t == 0) {
            enorm[k] = red[0] + red[1] + red[2] + red[3];
            counts[k] = 0u;
        }
    }
}

// ---------- 2) MX-scaled fp8 MFMA GEMM (32x32x64, unit scales) with fused argmin ----------
// One v_mfma_scale_f32_32x32x64_f8f6f4 consumes a full BK=64 K-slab per 32x32
// block at 2.27x the non-scaled fp8 rate. Per wave (128x64 output): 4 mb x 2 nb
// = 8 MFMA per K-tile. Fragment: lane holds row=lane&31, k=(lane>>5)*32+j
// (j=0..31) -> two b128 LDS reads (granules 2h,2h+1, swizzled); conflict-free
// under the same granule swizzle (uniform 8 dwords/bank). Ring-3 LDS, counted
// vmcnt(4), 2 phases per K-tile.
// NOTE: LDS (104 KB) limits to 1 block/CU regardless, so declare min-waves=1:
// raises the VGPR cap to 256 (acc alone is 128) -- (512,2) capped at 128 and
// spilled the accumulators to scratch (1.2 GB/dispatch of HBM traffic, r4).
__global__ __launch_bounds__(512, 1) void gemm_argmin(const unsigned char* __restrict__ z8,
                                                      const unsigned char* __restrict__ e8,
                                                      const float* __restrict__ enorm,
                                                      float* __restrict__ bestv,
                                                      int* __restrict__ besti) {
    __shared__ __align__(16) unsigned char smem[3 * TILE_STRIDE];   // 96 KB ring
    __shared__ float s_bv[4][BM];
    __shared__ int   s_bi[4][BM];

    const int tid  = threadIdx.x;
    const int m0   = blockIdx.x * BM;
    const int g    = blockIdx.y;
    const int c0   = g * BN;

    const int lane = tid & 63;
    const int w    = tid >> 6;        // 0..7
    const int wy   = w >> 2;          // m half (128 rows)
    const int wx   = w & 3;           // n quarter (64 cols)
    const int l31  = lane & 31;
    const int h    = lane >> 5;       // k-half selector of the fragment

    const unsigned char* gA = z8 + (size_t)m0 * CDIM;
    const unsigned char* gB = e8 + (size_t)c0 * CDIM;

    // staging geometry: thread stages LDS granule-slots s_lo=tid, s_hi=512+tid
    const int s_lo = tid;
    const int s_hi = 512 + tid;
    const int r_lo = s_lo >> 2, g_lo = swz(s_lo & 3, r_lo);
    const int r_hi = s_hi >> 2, g_hi = swz(s_hi & 3, r_hi);
    const size_t offA_lo = (size_t)r_lo * CDIM + g_lo * 16;
    const size_t offA_hi = (size_t)r_hi * CDIM + g_hi * 16;

    // loop-invariant LDS fragment offsets (lo granule; hi = lo ^ 16)
    int aoff[4], boff[2];
    #pragma unroll
    for (int mb = 0; mb < 4; ++mb) {
        int r = wy * 128 + mb * 32 + l31;
        aoff[mb] = r * BK + swz(2 * h, r) * 16;
    }
    #pragma unroll
    for (int nb = 0; nb < 2; ++nb) {
        int r = wx * 64 + nb * 32 + l31;
        boff[nb] = BM * BK + r * BK + swz(2 * h, r) * 16;
    }

    // ---- prologue: stage tiles 0 and 1 (4 sets each) ----
    #pragma unroll
    for (int tt = 0; tt < 2; ++tt) {
        unsigned char* lA = smem + tt * TILE_STRIDE;
        unsigned char* lB = lA + BM * BK;
        async_load16(gA + offA_lo + tt * BK, lA + s_lo * 16);
        async_load16(gA + offA_hi + tt * BK, lA + s_hi * 16);
        async_load16(gB + offA_lo + tt * BK, lB + s_lo * 16);
        async_load16(gB + offA_hi + tt * BK, lB + s_hi * 16);
    }
    asm volatile("s_waitcnt vmcnt(4)" ::: "memory");   // tile 0 landed; tile 1 in flight
    BARM();

    f32x16 acc[4][2] = {};

#define FRAG(dst, base, off) { \
    int4 lo_ = *(const int4*)((base) + (off));        \
    int4 hi_ = *(const int4*)((base) + ((off) ^ 16)); \
    dst = (i32x8){lo_.x, lo_.y, lo_.z, lo_.w, hi_.x, hi_.y, hi_.z, hi_.w}; }

    int cur = 0, stg = 2;
    for (int t = 0; t < KSTEPS; ++t) {
        const unsigned char* As = smem + cur * TILE_STRIDE;
        unsigned char* pA = smem + stg * TILE_STRIDE;
        unsigned char* pB = pA + BM * BK;
        const bool dostage = (t + 2 < KSTEPS);
        const size_t koff2 = (size_t)(t + 2) * BK;

        i32x8 bf0, bf1, af0, af1, af2, af3;

        // ---- P0: read B + A(mb0,mb1); stage A(t+2); MFMA mb0/mb1 x nb0/nb1 ----
        FRAG(bf0, As, boff[0]); FRAG(bf1, As, boff[1]);
        FRAG(af0, As, aoff[0]); FRAG(af1, As, aoff[1]);
        if (dostage) {
            async_load16(gA + offA_lo + koff2, pA + s_lo * 16);
            async_load16(gA + offA_hi + koff2, pA + s_hi * 16);
        }
        BARM();
        asm volatile("s_waitcnt lgkmcnt(0)" ::: "memory");
        SB0();
        __builtin_amdgcn_s_setprio(1);
        acc[0][0] = __builtin_amdgcn_mfma_scale_f32_32x32x64_f8f6f4(af0, bf0, acc[0][0], 0, 0, 0, SCALE1, 0, SCALE1);
        acc[0][1] = __builtin_amdgcn_mfma_scale_f32_32x32x64_f8f6f4(af0, bf1, acc[0][1], 0, 0, 0, SCALE1, 0, SCALE1);
        acc[1][0] = __builtin_amdgcn_mfma_scale_f32_32x32x64_f8f6f4(af1, bf0, acc[1][0], 0, 0, 0, SCALE1, 0, SCALE1);
        acc[1][1] = __builtin_amdgcn_mfma_scale_f32_32x32x64_f8f6f4(af1, bf1, acc[1][1], 0, 0, 0, SCALE1, 0, SCALE1);
        __builtin_amdgcn_s_setprio(0);
        SB0();
        BARM();

        // ---- P1: read A(mb2,mb3); stage B(t+2); MFMA mb2/mb3 x nb0/nb1; boundary ----
        FRAG(af2, As, aoff[2]); FRAG(af3, As, aoff[3]);
        if (dostage) {
            async_load16(gB + offA_lo + koff2, pB + s_lo * 16);
            async_load16(gB + offA_hi + koff2, pB + s_hi * 16);
        }
        BARM();
        asm volatile("s_waitcnt lgkmcnt(0)" ::: "memory");
        SB0();
        __builtin_amdgcn_s_setprio(1);
        acc[2][0] = __builtin_amdgcn_mfma_scale_f32_32x32x64_f8f6f4(af2, bf0, acc[2][0], 0, 0, 0, SCALE1, 0, SCALE1);
        acc[2][1] = __builtin_amdgcn_mfma_scale_f32_32x32x64_f8f6f4(af2, bf1, acc[2][1], 0, 0, 0, SCALE1, 0, SCALE1);
        acc[3][0] = __builtin_amdgcn_mfma_scale_f32_32x32x64_f8f6f4(af3, bf0, acc[3][0], 0, 0, 0, SCALE1, 0, SCALE1);
        acc[3][1] = __builtin_amdgcn_mfma_scale_f32_32x32x64_f8f6f4(af3, bf1, acc[3][1], 0, 0, 0, SCALE1, 0, SCALE1);
        __builtin_amdgcn_s_setprio(0);
        SB0();
        if (t < KSTEPS - 2)       asm volatile("s_waitcnt vmcnt(4)" ::: "memory");
        else if (t == KSTEPS - 2) asm volatile("s_waitcnt vmcnt(0)" ::: "memory");
        BARM();

        cur = (cur == 2) ? 0 : cur + 1;
        stg = (stg == 2) ? 0 : stg + 1;
    }

    // ---- epilogue: score = enorm - (2/ESCALE)*dot, per-row argmin ----
    // C layout (32x32, verified shape-determined): col = lane&31,
    // row = (p&3) + 8*(p>>2) + 4*(lane>>5).
    const int colbase = c0 + wx * 64 + l31;
    const float en0 = enorm[colbase];
    const float en1 = enorm[colbase + 32];
    #pragma unroll
    for (int mb = 0; mb < 4; ++mb) {
        #pragma unroll
        for (int p = 0; p < 16; ++p) {
            float v   = fmaf(-INV2ESCALE, acc[mb][0][p], en0);
            int   idx = colbase;
            float v1  = fmaf(-INV2ESCALE, acc[mb][1][p], en1);
            if (v1 < v) { v = v1; idx = colbase + 32; }
            #pragma unroll
            for (int msk = 1; msk < 32; msk <<= 1) {
                float ov = __shfl_xor(v, msk);
                int   oi = __shfl_xor(idx, msk);
                if (ov < v || (ov == v && oi < idx)) { v = ov; idx = oi; }
            }
            if (l31 == 0) {
                int row = wy * 128 + mb * 32 + (p & 3) + 8 * (p >> 2) + 4 * h;
                s_bv[wx][row] = v; s_bi[wx][row] = idx;
            }
        }
    }

    __syncthreads();
    if (tid < BM) {
        float v = s_bv[0][tid]; int ix = s_bi[0][tid];
        #pragma unroll
        for (int x = 1; x < 4; ++x) {
            float v2 = s_bv[x][tid]; int i2 = s_bi[x][tid];
            if (v2 < v || (v2 == v && i2 < ix)) { v = v2; ix = i2; }
        }
        bestv[(size_t)g * NROWS + m0 + tid] = v;
        besti[(size_t)g * NROWS + m0 + tid] = ix;
    }
}

// ---------- 3) combine groups, gather z_q, histogram ----------
__global__ __launch_bounds__(256) void gather_hist(const float* __restrict__ bestv,
                                                   const int* __restrict__ besti,
                                                   const float* __restrict__ e,
                                                   float* __restrict__ out,
                                                   unsigned int* __restrict__ counts) {
    int w    = threadIdx.x >> 6;
    int lane = threadIdx.x & 63;
    int n    = blockIdx.x * 4 + w;            // 8192 blocks * 4 waves = 32768 rows

    float v = bestv[n];
    int   idx = besti[n];
    #pragma unroll
    for (int g = 1; g < NGROUPS; ++g) {
        float v2 = bestv[(size_t)g * NROWS + n];
        int   i2 = besti[(size_t)g * NROWS + n];
        if (v2 < v || (v2 == v && i2 < idx)) { v = v2; idx = i2; }
    }
    if (lane == 0) atomicAdd(&counts[idx], 1u);

    const float4* src = (const float4*)(e + (size_t)idx * CDIM);
    float4*       dst = (float4*)(out + (size_t)n * CDIM);
    #pragma unroll
    for (int t = 0; t < 3; ++t)               // 192 float4 per row / 64 lanes
        dst[t * 64 + lane] = src[t * 64 + lane];
}

// ---------- 4) perplexity ----------
__global__ __launch_bounds__(256) void perplexity_k(const unsigned int* __restrict__ counts,
                                                    float* __restrict__ out) {
    int t = threadIdx.x;
    float s = 0.f;
    for (int k = t; k < NCODES; k += 256) {
        float p = (float)counts[k] * (1.0f / (float)NROWS);
        s += p * logf(p + 1e-10f);
    }
    #pragma unroll
    for (int o = 32; o > 0; o >>= 1) s += __shfl_down(s, o);
    __shared__ float red[4];
    if ((t & 63) == 0) red[t >> 6] = s;
    __syncthreads();
    if (t == 0) {
        float tot = red[0] + red[1] + red[2] + red[3];
        out[(size_t)NROWS * CDIM]     = 0.0f;        // vq_loss (eval mode)
        out[(size_t)NROWS * CDIM + 1] = expf(-tot);  // perplexity
    }
}

extern "C" void kernel_launch(void* const* d_in, const int* in_sizes, int n_in,
                              void* d_out, int out_size, void* d_ws, size_t ws_size,
                              hipStream_t stream) {
    const float* z = (const float*)d_in[0];   // [8,4096,768] fp32
    const float* e = (const float*)d_in[1];   // [2048,768]  fp32
    float* out = (float*)d_out;

    // workspace layout (all 16B aligned); total ~27.6 MB
    char* ws = (char*)d_ws;
    unsigned char* z8   = (unsigned char*)ws;  ws += (size_t)NROWS * CDIM;          // 24 MB
    unsigned char* e8   = (unsigned char*)ws;  ws += (size_t)NCODES * CDIM;         // 1.5 MB
    float* enorm        = (float*)ws;          ws += (size_t)NCODES * 4;            // 8 KB
    float* bestv        = (float*)ws;          ws += (size_t)NGROUPS * NROWS * 4;   // 1 MB
    int*   besti        = (int*)ws;            ws += (size_t)NGROUPS * NROWS * 4;   // 1 MB
    unsigned int* counts = (unsigned int*)ws;  ws += (size_t)NCODES * 4;            // 8 KB

    convert_fused<<<ZBLOCKS + NCODES, 256, 0, stream>>>(z, e, z8, e8, enorm, counts);
    dim3 gg(NROWS / BM, NGROUPS);             // 128 x 8
    gemm_argmin<<<gg, 512, 0, stream>>>(z8, e8, enorm, bestv, besti);
    gather_hist<<<NROWS / 4, 256, 0, stream>>>(bestv, besti, e, out, counts);
    perplexity_k<<<1, 256, 0, stream>>>(counts, out);
}

// Round 6
// 490.340 us; speedup vs baseline: 1.2784x; 1.2784x over previous
//
#include <hip/hip_runtime.h>
#include <hip/hip_bf16.h>
#include <stdint.h>
#include <math.h>

// Problem constants (fixed by reference)
#define NROWS   32768      // 8*4096
#define CDIM    768
#define NCODES  2048
#define NGROUPS 8          // col-groups (one 256-wide n-tile per group)
#define BM 128
#define BN 256
#define BK 64
#define KSTEPS (CDIM / BK)                  // 12
#define ESCALE 2048.0f                      // 2^11: lifts e into e4m3 range
#define INV2ESCALE (2.0f / ESCALE)          // folds the "-2 * dot" back
#define TILE_STRIDE ((BM + BN) * BK)        // A+B per ring slot (24 KB)
#define SCALE1 0x7F7F7F7F                   // E8M0 = 127 in every byte -> x1.0

typedef __attribute__((ext_vector_type(16))) float f32x16;
typedef __attribute__((ext_vector_type(8)))  int   i32x8;

#define BARM() asm volatile("s_barrier" ::: "memory")
#define SB0()  __builtin_amdgcn_sched_barrier(0)

// ---------- helpers ----------
__device__ __forceinline__ void async_load16(const void* gsrc, void* ldst) {
    __builtin_amdgcn_global_load_lds(
        (const __attribute__((address_space(1))) unsigned int*)gsrc,
        (__attribute__((address_space(3))) unsigned int*)ldst,
        16 /*bytes*/, 0 /*offset*/, 0 /*aux*/);
}

__device__ __forceinline__ unsigned int pack4_fp8(float x, float y, float z, float w) {
    int v = __builtin_amdgcn_cvt_pk_fp8_f32(x, y, 0, false);   // bytes 0,1
    v     = __builtin_amdgcn_cvt_pk_fp8_f32(z, w, v, true);    // bytes 2,3
    return (unsigned int)v;
}

// granule swizzle: LDS slot sl of row r holds global granule sl ^ ((r>>1)&3)
// (XOR involution: reader wanting global granule g reads slot g ^ ((r>>1)&3)).
__device__ __forceinline__ int swz(int sl, int r) { return sl ^ ((r >> 1) & 3); }

// ---------- 1) fused: z -> fp8  AND  e -> fp8*2048 + ||e||^2 + zero hist ----------
#define ZBLOCKS 6144       // 25165824 elems / (256 thr * 16 elem)
__global__ __launch_bounds__(256) void convert_fused(const float* __restrict__ z,
                                                     const float* __restrict__ e,
                                                     unsigned char* __restrict__ z8,
                                                     unsigned char* __restrict__ e8,
                                                     float* __restrict__ enorm,
                                                     unsigned int* __restrict__ counts) {
    int b = blockIdx.x;
    if (b < ZBLOCKS) {
        // fully-coalesced: each instruction's 64 lanes touch 1 KB contiguous
        const float4* zp = (const float4*)z + (size_t)b * 1024;
        unsigned int* o8 = (unsigned int*)z8 + (size_t)b * 1024;
        #pragma unroll
        for (int k2 = 0; k2 < 4; ++k2) {
            float4 a = zp[k2 * 256 + threadIdx.x];
            o8[k2 * 256 + threadIdx.x] = pack4_fp8(a.x, a.y, a.z, a.w);
        }
    } else {
        int k = b - ZBLOCKS;                      // one code per block
        int t = threadIdx.x;
        float s = 0.f;
        if (t < 192) {                            // 192 * 4 = 768 elems
            float4 v = ((const float4*)(e + (size_t)k * CDIM))[t];
            s = v.x * v.x + v.y * v.y + v.z * v.z + v.w * v.w;
            ((unsigned int*)(e8 + (size_t)k * CDIM))[t] =
                pack4_fp8(v.x * ESCALE, v.y * ESCALE, v.z * ESCALE, v.w * ESCALE);
        }
        #pragma unroll
        for (int o = 32; o > 0; o >>= 1) s += __shfl_down(s, o);
        __shared__ float red[4];
        if ((t & 63) == 0) red[t >> 6] = s;
        __syncthreads();
        if (t == 0) {
            enorm[k] = red[0] + red[1] + red[2] + red[3];
            counts[k] = 0u;
        }
    }
}

// ---------- 2) MX-scaled fp8 MFMA GEMM (32x32x64, unit scales) with fused argmin ----------
// r5 lesson: 512-thr WG empirically caps at 128 VGPR (both launch-bound
// settings) and a 128-reg accumulator then spills ~24 regs/K-tile -> 1.2 GB
// scratch traffic/dispatch. Fix by construction: wave tile 64x64 (4 MFMA
// tiles = 64 acc VGPRs). 8 waves = 2(wy) x 4(wx); block = 128x256.
// Peak live ~120 VGPR < 128. Ring-3 LDS (72 KB), 1 barrier + counted
// vmcnt(3)/K-tile; same verified granule swizzle (zero conflicts, r3).
__global__ __launch_bounds__(512, 1) void gemm_argmin(const unsigned char* __restrict__ z8,
                                                      const unsigned char* __restrict__ e8,
                                                      const float* __restrict__ enorm,
                                                      float* __restrict__ bestv,
                                                      int* __restrict__ besti) {
    __shared__ __align__(16) unsigned char smem[3 * TILE_STRIDE];   // 72 KB ring
    __shared__ float s_bv[4][BM];
    __shared__ int   s_bi[4][BM];

    const int tid  = threadIdx.x;
    const int m0   = blockIdx.x * BM;
    const int g    = blockIdx.y;
    const int c0   = g * BN;

    const int lane = tid & 63;
    const int w    = tid >> 6;        // 0..7
    const int wy   = w >> 2;          // m half (64 rows each)
    const int wx   = w & 3;           // n quarter (64 cols each)
    const int l31  = lane & 31;
    const int h    = lane >> 5;       // k-half selector of the fragment

    const unsigned char* gA = z8 + (size_t)m0 * CDIM;
    const unsigned char* gB = e8 + (size_t)c0 * CDIM;

    // staging geometry: per K-tile, thread stages A granule tid, B granules
    // tid and 512+tid. B row+128 keeps (r>>1)&3 unchanged -> same column swz.
    const int ra   = tid >> 2;
    const int ga   = swz(tid & 3, ra);
    const size_t offG = (size_t)ra * CDIM + ga * 16;   // A, B-lo; B-hi adds 128 rows
    const int ldsA  = tid * 16;
    const int ldsB0 = BM * BK + tid * 16;
    const int ldsB1 = BM * BK + (512 + tid) * 16;

    // loop-invariant LDS fragment byte offsets (lo granule; hi = lo ^ 16)
    int ra0 = wy * 64 + l31,        ra1 = ra0 + 32;
    int rb0 = wx * 64 + l31,        rb1 = rb0 + 32;
    const int aoff0 = ra0 * BK + swz(2 * h, ra0) * 16;
    const int aoff1 = ra1 * BK + swz(2 * h, ra1) * 16;
    const int boff0 = BM * BK + rb0 * BK + swz(2 * h, rb0) * 16;
    const int boff1 = BM * BK + rb1 * BK + swz(2 * h, rb1) * 16;

    // ---- prologue: stage tiles 0 and 1 (3 loads each) ----
    #pragma unroll
    for (int tt = 0; tt < 2; ++tt) {
        unsigned char* lbase = smem + tt * TILE_STRIDE;
        async_load16(gA + offG + tt * BK,                      lbase + ldsA);
        async_load16(gB + offG + tt * BK,                      lbase + ldsB0);
        async_load16(gB + offG + (size_t)128 * CDIM + tt * BK, lbase + ldsB1);
    }
    asm volatile("s_waitcnt vmcnt(3)" ::: "memory");   // tile 0 landed; tile 1 in flight
    BARM();

    f32x16 acc00 = {}, acc01 = {}, acc10 = {}, acc11 = {};

#define FRAG(dst, base, off) { \
    int4 lo_ = *(const int4*)((base) + (off));        \
    int4 hi_ = *(const int4*)((base) + ((off) ^ 16)); \
    dst = (i32x8){lo_.x, lo_.y, lo_.z, lo_.w, hi_.x, hi_.y, hi_.z, hi_.w}; }

    int cur = 0, stg = 2;
    for (int t = 0; t < KSTEPS; ++t) {
        const unsigned char* As = smem + cur * TILE_STRIDE;
        unsigned char* ps = smem + stg * TILE_STRIDE;
        const size_t koff2 = (size_t)(t + 2) * BK;

        // issue-early prefetch of tile t+2 (slot = (t-1)%3, free since last barrier)
        if (t + 2 < KSTEPS) {
            async_load16(gA + offG + koff2,                      ps + ldsA);
            async_load16(gB + offG + koff2,                      ps + ldsB0);
            async_load16(gB + offG + (size_t)128 * CDIM + koff2, ps + ldsB1);
        }

        i32x8 a0, a1, b0, b1;
        FRAG(a0, As, aoff0); FRAG(a1, As, aoff1);
        FRAG(b0, As, boff0); FRAG(b1, As, boff1);
        asm volatile("s_waitcnt lgkmcnt(0)" ::: "memory");
        SB0();
        __builtin_amdgcn_s_setprio(1);
        acc00 = __builtin_amdgcn_mfma_scale_f32_32x32x64_f8f6f4(a0, b0, acc00, 0, 0, 0, SCALE1, 0, SCALE1);
        acc01 = __builtin_amdgcn_mfma_scale_f32_32x32x64_f8f6f4(a0, b1, acc01, 0, 0, 0, SCALE1, 0, SCALE1);
        acc10 = __builtin_amdgcn_mfma_scale_f32_32x32x64_f8f6f4(a1, b0, acc10, 0, 0, 0, SCALE1, 0, SCALE1);
        acc11 = __builtin_amdgcn_mfma_scale_f32_32x32x64_f8f6f4(a1, b1, acc11, 0, 0, 0, SCALE1, 0, SCALE1);
        __builtin_amdgcn_s_setprio(0);
        SB0();

        // boundary: tile t+1 must be resident; keep t+2's 3 loads in flight
        if (t < KSTEPS - 2)       asm volatile("s_waitcnt vmcnt(3)" ::: "memory");
        else if (t == KSTEPS - 2) asm volatile("s_waitcnt vmcnt(0)" ::: "memory");
        BARM();

        cur = (cur == 2) ? 0 : cur + 1;
        stg = (stg == 2) ? 0 : stg + 1;
    }

    // ---- epilogue: score = enorm - (2/ESCALE)*dot, per-row argmin ----
    // C layout (32x32, verified r4/r5): col = lane&31,
    // row = (p&3) + 8*(p>>2) + 4*(lane>>5).
    const int colbase = c0 + wx * 64 + l31;
    const float en0 = enorm[colbase];
    const float en1 = enorm[colbase + 32];

#define EPILOG(ACC0, ACC1, MB)                                              \
    _Pragma("unroll")                                                       \
    for (int p = 0; p < 16; ++p) {                                          \
        float v   = fmaf(-INV2ESCALE, ACC0[p], en0);                        \
        int   idx = colbase;                                                \
        float v1  = fmaf(-INV2ESCALE, ACC1[p], en1);                        \
        if (v1 < v) { v = v1; idx = colbase + 32; }                         \
        _Pragma("unroll")                                                   \
        for (int msk = 1; msk < 32; msk <<= 1) {                            \
            float ov = __shfl_xor(v, msk);                                  \
            int   oi = __shfl_xor(idx, msk);                                \
            if (ov < v || (ov == v && oi < idx)) { v = ov; idx = oi; }      \
        }                                                                   \
        if (l31 == 0) {                                                     \
            int row = wy * 64 + (MB) * 32 + (p & 3) + 8 * (p >> 2) + 4 * h; \
            s_bv[wx][row] = v; s_bi[wx][row] = idx;                         \
        }                                                                   \
    }

    EPILOG(acc00, acc01, 0)
    EPILOG(acc10, acc11, 1)

    __syncthreads();
    if (tid < BM) {
        float v = s_bv[0][tid]; int ix = s_bi[0][tid];
        #pragma unroll
        for (int x = 1; x < 4; ++x) {
            float v2 = s_bv[x][tid]; int i2 = s_bi[x][tid];
            if (v2 < v || (v2 == v && i2 < ix)) { v = v2; ix = i2; }
        }
        bestv[(size_t)g * NROWS + m0 + tid] = v;
        besti[(size_t)g * NROWS + m0 + tid] = ix;
    }
}

// ---------- 3) combine groups, gather z_q, histogram ----------
__global__ __launch_bounds__(256) void gather_hist(const float* __restrict__ bestv,
                                                   const int* __restrict__ besti,
                                                   const float* __restrict__ e,
                                                   float* __restrict__ out,
                                                   unsigned int* __restrict__ counts) {
    int w    = threadIdx.x >> 6;
    int lane = threadIdx.x & 63;
    int n    = blockIdx.x * 4 + w;            // 8192 blocks * 4 waves = 32768 rows

    float v = bestv[n];
    int   idx = besti[n];
    #pragma unroll
    for (int g = 1; g < NGROUPS; ++g) {
        float v2 = bestv[(size_t)g * NROWS + n];
        int   i2 = besti[(size_t)g * NROWS + n];
        if (v2 < v || (v2 == v && i2 < idx)) { v = v2; idx = i2; }
    }
    if (lane == 0) atomicAdd(&counts[idx], 1u);

    const float4* src = (const float4*)(e + (size_t)idx * CDIM);
    float4*       dst = (float4*)(out + (size_t)n * CDIM);
    #pragma unroll
    for (int t = 0; t < 3; ++t)               // 192 float4 per row / 64 lanes
        dst[t * 64 + lane] = src[t * 64 + lane];
}

// ---------- 4) perplexity ----------
__global__ __launch_bounds__(256) void perplexity_k(const unsigned int* __restrict__ counts,
                                                    float* __restrict__ out) {
    int t = threadIdx.x;
    float s = 0.f;
    for (int k = t; k < NCODES; k += 256) {
        float p = (float)counts[k] * (1.0f / (float)NROWS);
        s += p * logf(p + 1e-10f);
    }
    #pragma unroll
    for (int o = 32; o > 0; o >>= 1) s += __shfl_down(s, o);
    __shared__ float red[4];
    if ((t & 63) == 0) red[t >> 6] = s;
    __syncthreads();
    if (t == 0) {
        float tot = red[0] + red[1] + red[2] + red[3];
        out[(size_t)NROWS * CDIM]     = 0.0f;        // vq_loss (eval mode)
        out[(size_t)NROWS * CDIM + 1] = expf(-tot);  // perplexity
    }
}

extern "C" void kernel_launch(void* const* d_in, const int* in_sizes, int n_in,
                              void* d_out, int out_size, void* d_ws, size_t ws_size,
                              hipStream_t stream) {
    const float* z = (const float*)d_in[0];   // [8,4096,768] fp32
    const float* e = (const float*)d_in[1];   // [2048,768]  fp32
    float* out = (float*)d_out;

    // workspace layout (all 16B aligned); total ~27.6 MB
    char* ws = (char*)d_ws;
    unsigned char* z8   = (unsigned char*)ws;  ws += (size_t)NROWS * CDIM;          // 24 MB
    unsigned char* e8   = (unsigned char*)ws;  ws += (size_t)NCODES * CDIM;         // 1.5 MB
    float* enorm        = (float*)ws;          ws += (size_t)NCODES * 4;            // 8 KB
    float* bestv        = (float*)ws;          ws += (size_t)NGROUPS * NROWS * 4;   // 1 MB
    int*   besti        = (int*)ws;            ws += (size_t)NGROUPS * NROWS * 4;   // 1 MB
    unsigned int* counts = (unsigned int*)ws;  ws += (size_t)NCODES * 4;            // 8 KB

    convert_fused<<<ZBLOCKS + NCODES, 256, 0, stream>>>(z, e, z8, e8, enorm, counts);
    dim3 gg(NROWS / BM, NGROUPS);             // 256 x 8
    gemm_argmin<<<gg, 512, 0, stream>>>(z8, e8, enorm, bestv, besti);
    gather_hist<<<NROWS / 4, 256, 0, stream>>>(bestv, besti, e, out, counts);
    perplexity_k<<<1, 256, 0, stream>>>(counts, out);
}

// Round 7
// 488.423 us; speedup vs baseline: 1.2834x; 1.0039x over previous
//
#include <hip/hip_runtime.h>
#include <hip/hip_bf16.h>
#include <stdint.h>
#include <math.h>

// Problem constants (fixed by reference)
#define NROWS   32768      // 8*4096
#define CDIM    768
#define NCODES  2048
#define NGROUPS 8          // col-groups (one 256-wide n-tile per group)
#define BM 128
#define BN 256
#define BK 64
#define KSTEPS (CDIM / BK)                  // 12
#define ESCALE 2048.0f                      // 2^11: lifts e into e4m3 range
#define INV2ESCALE (2.0f / ESCALE)          // folds the "-2 * dot" back
#define TILE_STRIDE ((BM + BN) * BK)        // A+B per ring slot (24 KB)
#define SCALE1 0x7F7F7F7F                   // E8M0 = 127 in every byte -> x1.0
// LDS pad: push block LDS past 80 KB so only 1 WG/CU fits. The backend
// derives its VGPR budget from LDS-allowed occupancy (r3..r6 evidence:
// 104KB->budget 256, no spill; 76KB->2 WG/CU->budget 128 -> 24-reg spill,
// 700 MB scratch). 82 KB -> 2 waves/SIMD -> 256-reg budget.
#define LDS_PAD 6144

typedef __attribute__((ext_vector_type(16))) float f32x16;
typedef __attribute__((ext_vector_type(8)))  int   i32x8;

#define BARM() asm volatile("s_barrier" ::: "memory")
#define SB0()  __builtin_amdgcn_sched_barrier(0)

// ---------- helpers ----------
__device__ __forceinline__ void async_load16(const void* gsrc, void* ldst) {
    __builtin_amdgcn_global_load_lds(
        (const __attribute__((address_space(1))) unsigned int*)gsrc,
        (__attribute__((address_space(3))) unsigned int*)ldst,
        16 /*bytes*/, 0 /*offset*/, 0 /*aux*/);
}

__device__ __forceinline__ unsigned int pack4_fp8(float x, float y, float z, float w) {
    int v = __builtin_amdgcn_cvt_pk_fp8_f32(x, y, 0, false);   // bytes 0,1
    v     = __builtin_amdgcn_cvt_pk_fp8_f32(z, w, v, true);    // bytes 2,3
    return (unsigned int)v;
}

// granule swizzle: LDS slot sl of row r holds global granule sl ^ ((r>>1)&3)
// (XOR involution: reader wanting global granule g reads slot g ^ ((r>>1)&3)).
__device__ __forceinline__ int swz(int sl, int r) { return sl ^ ((r >> 1) & 3); }

// ---------- 1) fused: z -> fp8  AND  e -> fp8*2048 + ||e||^2 + zero hist ----------
#define ZBLOCKS 6144       // 25165824 elems / (256 thr * 16 elem)
__global__ __launch_bounds__(256) void convert_fused(const float* __restrict__ z,
                                                     const float* __restrict__ e,
                                                     unsigned char* __restrict__ z8,
                                                     unsigned char* __restrict__ e8,
                                                     float* __restrict__ enorm,
                                                     unsigned int* __restrict__ counts) {
    int b = blockIdx.x;
    if (b < ZBLOCKS) {
        // fully-coalesced: each instruction's 64 lanes touch 1 KB contiguous
        const float4* zp = (const float4*)z + (size_t)b * 1024;
        unsigned int* o8 = (unsigned int*)z8 + (size_t)b * 1024;
        #pragma unroll
        for (int k2 = 0; k2 < 4; ++k2) {
            float4 a = zp[k2 * 256 + threadIdx.x];
            o8[k2 * 256 + threadIdx.x] = pack4_fp8(a.x, a.y, a.z, a.w);
        }
    } else {
        int k = b - ZBLOCKS;                      // one code per block
        int t = threadIdx.x;
        float s = 0.f;
        if (t < 192) {                            // 192 * 4 = 768 elems
            float4 v = ((const float4*)(e + (size_t)k * CDIM))[t];
            s = v.x * v.x + v.y * v.y + v.z * v.z + v.w * v.w;
            ((unsigned int*)(e8 + (size_t)k * CDIM))[t] =
                pack4_fp8(v.x * ESCALE, v.y * ESCALE, v.z * ESCALE, v.w * ESCALE);
        }
        #pragma unroll
        for (int o = 32; o > 0; o >>= 1) s += __shfl_down(s, o);
        __shared__ float red[4];
        if ((t & 63) == 0) red[t >> 6] = s;
        __syncthreads();
        if (t == 0) {
            enorm[k] = red[0] + red[1] + red[2] + red[3];
            counts[k] = 0u;
        }
    }
}

// ---------- 2) MX-scaled fp8 MFMA GEMM (32x32x64, unit scales) with fused argmin ----------
// Wave tile 64x64 (4 MFMA tiles = 64 acc VGPRs), 8 waves = 2(wy) x 4(wx),
// block 128x256. Ring-3 LDS, 1 barrier + counted vmcnt(3)/K-tile, verified
// granule swizzle. Register budget pinned at 256 via LDS_PAD (see above)
// + amdgpu_waves_per_eu(2,2) -> no accumulator spill.
__global__ __launch_bounds__(512)
__attribute__((amdgpu_waves_per_eu(2, 2)))
void gemm_argmin(const unsigned char* __restrict__ z8,
                 const unsigned char* __restrict__ e8,
                 const float* __restrict__ enorm,
                 float* __restrict__ bestv,
                 int* __restrict__ besti) {
    __shared__ __align__(16) unsigned char smem[3 * TILE_STRIDE + LDS_PAD];
    __shared__ float s_bv[4][BM];
    __shared__ int   s_bi[4][BM];

    const int tid  = threadIdx.x;
    const int m0   = blockIdx.x * BM;
    const int g    = blockIdx.y;
    const int c0   = g * BN;

    const int lane = tid & 63;
    const int w    = tid >> 6;        // 0..7
    const int wy   = w >> 2;          // m half (64 rows each)
    const int wx   = w & 3;           // n quarter (64 cols each)
    const int l31  = lane & 31;
    const int h    = lane >> 5;       // k-half selector of the fragment

    const unsigned char* gA = z8 + (size_t)m0 * CDIM;
    const unsigned char* gB = e8 + (size_t)c0 * CDIM;

    // staging geometry: per K-tile, thread stages A granule tid, B granules
    // tid and 512+tid. B row+128 keeps (r>>1)&3 unchanged -> same column swz.
    const int ra   = tid >> 2;
    const int ga   = swz(tid & 3, ra);
    const size_t offG = (size_t)ra * CDIM + ga * 16;   // A, B-lo; B-hi adds 128 rows
    const int ldsA  = tid * 16;
    const int ldsB0 = BM * BK + tid * 16;
    const int ldsB1 = BM * BK + (512 + tid) * 16;

    // loop-invariant LDS fragment byte offsets (lo granule; hi = lo ^ 16)
    int ra0 = wy * 64 + l31,        ra1 = ra0 + 32;
    int rb0 = wx * 64 + l31,        rb1 = rb0 + 32;
    const int aoff0 = ra0 * BK + swz(2 * h, ra0) * 16;
    const int aoff1 = ra1 * BK + swz(2 * h, ra1) * 16;
    const int boff0 = BM * BK + rb0 * BK + swz(2 * h, rb0) * 16;
    const int boff1 = BM * BK + rb1 * BK + swz(2 * h, rb1) * 16;

    // ---- prologue: stage tiles 0 and 1 (3 loads each) ----
    #pragma unroll
    for (int tt = 0; tt < 2; ++tt) {
        unsigned char* lbase = smem + tt * TILE_STRIDE;
        async_load16(gA + offG + tt * BK,                      lbase + ldsA);
        async_load16(gB + offG + tt * BK,                      lbase + ldsB0);
        async_load16(gB + offG + (size_t)128 * CDIM + tt * BK, lbase + ldsB1);
    }
    asm volatile("s_waitcnt vmcnt(3)" ::: "memory");   // tile 0 landed; tile 1 in flight
    BARM();

    f32x16 acc00 = {}, acc01 = {}, acc10 = {}, acc11 = {};

#define FRAG(dst, base, off) { \
    int4 lo_ = *(const int4*)((base) + (off));        \
    int4 hi_ = *(const int4*)((base) + ((off) ^ 16)); \
    dst = (i32x8){lo_.x, lo_.y, lo_.z, lo_.w, hi_.x, hi_.y, hi_.z, hi_.w}; }

    int cur = 0, stg = 2;
    for (int t = 0; t < KSTEPS; ++t) {
        const unsigned char* As = smem + cur * TILE_STRIDE;
        unsigned char* ps = smem + stg * TILE_STRIDE;
        const size_t koff2 = (size_t)(t + 2) * BK;

        // issue-early prefetch of tile t+2 (slot = (t-1)%3, free since last barrier)
        if (t + 2 < KSTEPS) {
            async_load16(gA + offG + koff2,                      ps + ldsA);
            async_load16(gB + offG + koff2,                      ps + ldsB0);
            async_load16(gB + offG + (size_t)128 * CDIM + koff2, ps + ldsB1);
        }

        i32x8 a0, a1, b0, b1;
        FRAG(a0, As, aoff0); FRAG(a1, As, aoff1);
        FRAG(b0, As, boff0); FRAG(b1, As, boff1);
        asm volatile("s_waitcnt lgkmcnt(0)" ::: "memory");
        SB0();
        __builtin_amdgcn_s_setprio(1);
        acc00 = __builtin_amdgcn_mfma_scale_f32_32x32x64_f8f6f4(a0, b0, acc00, 0, 0, 0, SCALE1, 0, SCALE1);
        acc01 = __builtin_amdgcn_mfma_scale_f32_32x32x64_f8f6f4(a0, b1, acc01, 0, 0, 0, SCALE1, 0, SCALE1);
        acc10 = __builtin_amdgcn_mfma_scale_f32_32x32x64_f8f6f4(a1, b0, acc10, 0, 0, 0, SCALE1, 0, SCALE1);
        acc11 = __builtin_amdgcn_mfma_scale_f32_32x32x64_f8f6f4(a1, b1, acc11, 0, 0, 0, SCALE1, 0, SCALE1);
        __builtin_amdgcn_s_setprio(0);
        SB0();

        // boundary: tile t+1 must be resident; keep t+2's 3 loads in flight
        if (t < KSTEPS - 2)       asm volatile("s_waitcnt vmcnt(3)" ::: "memory");
        else if (t == KSTEPS - 2) asm volatile("s_waitcnt vmcnt(0)" ::: "memory");
        BARM();

        cur = (cur == 2) ? 0 : cur + 1;
        stg = (stg == 2) ? 0 : stg + 1;
    }

    // ---- epilogue: score = enorm - (2/ESCALE)*dot, per-row argmin ----
    // C layout (32x32, verified r4/r5): col = lane&31,
    // row = (p&3) + 8*(p>>2) + 4*(lane>>5).
    const int colbase = c0 + wx * 64 + l31;
    const float en0 = enorm[colbase];
    const float en1 = enorm[colbase + 32];

#define EPILOG(ACC0, ACC1, MB)                                              \
    _Pragma("unroll")                                                       \
    for (int p = 0; p < 16; ++p) {                                          \
        float v   = fmaf(-INV2ESCALE, ACC0[p], en0);                        \
        int   idx = colbase;                                                \
        float v1  = fmaf(-INV2ESCALE, ACC1[p], en1);                        \
        if (v1 < v) { v = v1; idx = colbase + 32; }                         \
        _Pragma("unroll")                                                   \
        for (int msk = 1; msk < 32; msk <<= 1) {                            \
            float ov = __shfl_xor(v, msk);                                  \
            int   oi = __shfl_xor(idx, msk);                                \
            if (ov < v || (ov == v && oi < idx)) { v = ov; idx = oi; }      \
        }                                                                   \
        if (l31 == 0) {                                                     \
            int row = wy * 64 + (MB) * 32 + (p & 3) + 8 * (p >> 2) + 4 * h; \
            s_bv[wx][row] = v; s_bi[wx][row] = idx;                         \
        }                                                                   \
    }

    EPILOG(acc00, acc01, 0)
    EPILOG(acc10, acc11, 1)

    __syncthreads();
    if (tid < BM) {
        float v = s_bv[0][tid]; int ix = s_bi[0][tid];
        #pragma unroll
        for (int x = 1; x < 4; ++x) {
            float v2 = s_bv[x][tid]; int i2 = s_bi[x][tid];
            if (v2 < v || (v2 == v && i2 < ix)) { v = v2; ix = i2; }
        }
        bestv[(size_t)g * NROWS + m0 + tid] = v;
        besti[(size_t)g * NROWS + m0 + tid] = ix;
    }
}

// ---------- 3) combine groups, gather z_q, histogram ----------
__global__ __launch_bounds__(256) void gather_hist(const float* __restrict__ bestv,
                                                   const int* __restrict__ besti,
                                                   const float* __restrict__ e,
                                                   float* __restrict__ out,
                                                   unsigned int* __restrict__ counts) {
    int w    = threadIdx.x >> 6;
    int lane = threadIdx.x & 63;
    int n    = blockIdx.x * 4 + w;            // 8192 blocks * 4 waves = 32768 rows

    float v = bestv[n];
    int   idx = besti[n];
    #pragma unroll
    for (int g = 1; g < NGROUPS; ++g) {
        float v2 = bestv[(size_t)g * NROWS + n];
        int   i2 = besti[(size_t)g * NROWS + n];
        if (v2 < v || (v2 == v && i2 < idx)) { v = v2; idx = i2; }
    }
    if (lane == 0) atomicAdd(&counts[idx], 1u);

    const float4* src = (const float4*)(e + (size_t)idx * CDIM);
    float4*       dst = (float4*)(out + (size_t)n * CDIM);
    #pragma unroll
    for (int t = 0; t < 3; ++t)               // 192 float4 per row / 64 lanes
        dst[t * 64 + lane] = src[t * 64 + lane];
}

// ---------- 4) perplexity ----------
__global__ __launch_bounds__(256) void perplexity_k(const unsigned int* __restrict__ counts,
                                                    float* __restrict__ out) {
    int t = threadIdx.x;
    float s = 0.f;
    for (int k = t; k < NCODES; k += 256) {
        float p = (float)counts[k] * (1.0f / (float)NROWS);
        s += p * logf(p + 1e-10f);
    }
    #pragma unroll
    for (int o = 32; o > 0; o >>= 1) s += __shfl_down(s, o);
    __shared__ float red[4];
    if ((t & 63) == 0) red[t >> 6] = s;
    __syncthreads();
    if (t == 0) {
        float tot = red[0] + red[1] + red[2] + red[3];
        out[(size_t)NROWS * CDIM]     = 0.0f;        // vq_loss (eval mode)
        out[(size_t)NROWS * CDIM + 1] = expf(-tot);  // perplexity
    }
}

extern "C" void kernel_launch(void* const* d_in, const int* in_sizes, int n_in,
                              void* d_out, int out_size, void* d_ws, size_t ws_size,
                              hipStream_t stream) {
    const float* z = (const float*)d_in[0];   // [8,4096,768] fp32
    const float* e = (const float*)d_in[1];   // [2048,768]  fp32
    float* out = (float*)d_out;

    // workspace layout (all 16B aligned); total ~27.6 MB
    char* ws = (char*)d_ws;
    unsigned char* z8   = (unsigned char*)ws;  ws += (size_t)NROWS * CDIM;          // 24 MB
    unsigned char* e8   = (unsigned char*)ws;  ws += (size_t)NCODES * CDIM;         // 1.5 MB
    float* enorm        = (float*)ws;          ws += (size_t)NCODES * 4;            // 8 KB
    float* bestv        = (float*)ws;          ws += (size_t)NGROUPS * NROWS * 4;   // 1 MB
    int*   besti        = (int*)ws;            ws += (size_t)NGROUPS * NROWS * 4;   // 1 MB
    unsigned int* counts = (unsigned int*)ws;  ws += (size_t)NCODES * 4;            // 8 KB

    convert_fused<<<ZBLOCKS + NCODES, 256, 0, stream>>>(z, e, z8, e8, enorm, counts);
    dim3 gg(NROWS / BM, NGROUPS);             // 256 x 8
    gemm_argmin<<<gg, 512, 0, stream>>>(z8, e8, enorm, bestv, besti);
    gather_hist<<<NROWS / 4, 256, 0, stream>>>(bestv, besti, e, out, counts);
    perplexity_k<<<1, 256, 0, stream>>>(counts, out);
}